// Round 3
// baseline (272.233 us; speedup 1.0000x reference)
//
#include <hip/hip_runtime.h>
#include <hip/hip_bf16.h>

// ---------------------------------------------------------------------------
// EnsembleDynamicModel: E=7 MLPs, B=32768, dims 40->256->256->256->128->(32|32)
// Fully fused bf16-MFMA kernel with register software-pipelining.
//
// Round 3: ping-pong LDS activation buffers -> ONE barrier per layer.
// Round-0 paid 2 full-drain barriers per layer; the first existed only because
// the epilogue wrote into the same hs it had just read. With buf[l%2] ->
// buf[(l+1)%2] the in/out regions are disjoint: MFMA reads bufIn while the
// epilogue writes bufOut, and a single end-of-layer barrier both publishes the
// writes and retires the reads (bufIn becomes reusable). Sync points 10 -> 5.
// LDS 2x33792B = 67584B -> 2 blocks/CU (anti-phased -> s_setprio(1) on the
// MFMA loop per T5). Round-2 lesson: 8-wave/NTW=2 doubles ds_read A-traffic
// past the MFMA pipe (bank conflicts 6.9M->11M, LDS-bound); round-1 lesson:
// forcing 4 waves/EU spills (acc=64 AGPR is structural). So keep the round-0
// 4-wave NTW=4 shape (VGPR ~148 combined, 2-3 waves/EU natural, no bound).
//
// Activation layout: pair-interleaved columns: n-tile ntg col c -> physical
// col 32*(ntg>>1) + 2c + (ntg&1); weight packer applies inverse permutation
// to k for layers reading hidden activations. pack_w unchanged from round 0.
// ---------------------------------------------------------------------------

#define NE 7
#define NB 32768
#define PER_E 188416   // packed shorts per ensemble
#define HSTRIDE 264    // 256 + 8 pad (shorts)

typedef __attribute__((ext_vector_type(8))) short short8;   // 8 x bf16
typedef __attribute__((ext_vector_type(4))) float floatx4;  // MFMA C/D

__device__ __forceinline__ short f2b(float f) {
    union { float f; unsigned u; } c; c.f = f;
    return (short)((c.u + 0x7fffu + ((c.u >> 16) & 1u)) >> 16);
}
__device__ __forceinline__ unsigned pk2(float a, float b) {  // bf16x2 {lo=a,hi=b}
    union { __hip_bfloat162 h; unsigned u; } c;
    c.h = __float22bfloat162_rn(make_float2(a, b));
    return c.u;
}

// Packed-weight layout per ensemble (units: shorts):
//  L0 : off 0      KT=2 NT=16 Kact=40  N=256
//  L1 : off 16384  KT=8 NT=16 Kact=256 N=256
//  L2 : off 81920  KT=8 NT=16 Kact=256 N=256
//  L3 : off 147456 KT=8 NT=8  Kact=256 N=128
//  HD : off 180224 KT=4 NT=4  Kact=128 N=64   (mu cols 0..31 | sig 32..63)
__global__ void __launch_bounds__(256) pack_w(
    const float* __restrict__ W0, const float* __restrict__ W1,
    const float* __restrict__ W2, const float* __restrict__ W3,
    const float* __restrict__ Wmu, const float* __restrict__ Wsig,
    short* __restrict__ out)
{
    __shared__ float tile[32][65];
    const int t = threadIdx.x;
    int b = blockIdx.x;
    int e = b / 92;
    int r = b - e * 92;
    const float* src = W0;
    int off = 0, Kact = 40, N = 256, NT = 16, kt, ntb;
    bool inv = false, head = false;
    if (r < 8)       { kt = r >> 2; ntb = r & 3; }
    else if (r < 40) { r -= 8;  src = W1; off = 16384;  Kact = 256; kt = r >> 2; ntb = r & 3; inv = true; }
    else if (r < 72) { r -= 40; src = W2; off = 81920;  Kact = 256; kt = r >> 2; ntb = r & 3; inv = true; }
    else if (r < 88) { r -= 72; src = W3; off = 147456; Kact = 256; N = 128; NT = 8; kt = r >> 1; ntb = r & 1; inv = true; }
    else             { r -= 88; off = 180224; Kact = 128; N = 64; NT = 4; kt = r; ntb = 0; inv = true; head = true; }

#pragma unroll
    for (int i = 0; i < 8; ++i) {
        int elem  = t + i * 256;
        int row_l = elem >> 6, col_l = elem & 63;
        int gk = kt * 32 + row_l;
        int gn = ntb * 64 + col_l;
        float v = 0.f;
        if (gk < Kact) {
            if (head) v = (gn < 32) ? Wmu[((size_t)e * 128 + gk) * 32 + gn]
                                    : Wsig[((size_t)e * 128 + gk) * 32 + (gn - 32)];
            else      v = src[((size_t)e * Kact + gk) * N + gn];
        }
        tile[row_l][col_l] = v;
    }
    __syncthreads();

    const int f = t >> 6, lam = t & 63;
    const int lan = lam & 15, quad = lam >> 4;
    short8 o;
#pragma unroll
    for (int j = 0; j < 8; ++j) {
        int q  = quad * 8 + j;                              // physical k within 32-block
        int sr = inv ? (((q & 1) << 4) | (q >> 1)) : q;     // logical source row
        o[j] = f2b(tile[sr][f * 16 + lan]);
    }
    *(short8*)(out + (size_t)e * PER_E + off +
               ((size_t)(kt * NT + ntb * 4 + f) * 64 + lam) * 8) = o;
}

// One hidden layer, ping-pong: MFMA reads bufIn, epilogue writes bufOut,
// ONE barrier at the end (publishes writes + retires bufIn reads).
// bf0[NTW]: this layer's kt=0 B-frags (prefetched). nbf0[NNTW]: out — next
// layer's kt=0 B-frags, prefetched before the epilogue (swish hides L2 lat).
template<int KT, int NTW, int NT, int NNTW>
__device__ __forceinline__ void mlp_layer(const short* __restrict__ wpk,
                                          const float* __restrict__ bias,
                                          const short* bufIn, short* bufOut,
                                          const int wave, const int lane,
                                          const short8* bf0,
                                          const short* __restrict__ nwpk,
                                          short8* nbf0) {
    const int quad = lane >> 4;
    const int lan  = lane & 15;
    floatx4 acc[4][NTW];
#pragma unroll
    for (int mt = 0; mt < 4; ++mt)
#pragma unroll
        for (int nt = 0; nt < NTW; ++nt) acc[mt][nt] = floatx4{0.f, 0.f, 0.f, 0.f};

    short8 bfc[NTW], bfn[NTW];
#pragma unroll
    for (int nt = 0; nt < NTW; ++nt) bfc[nt] = bf0[nt];

    __builtin_amdgcn_s_setprio(1);   // T5: 2 anti-phased blocks/CU arbitrate
#pragma unroll
    for (int kt = 0; kt < KT; ++kt) {
        if (kt + 1 < KT) {   // prefetch next kt's B-frags before this kt's MFMAs
#pragma unroll
            for (int nt = 0; nt < NTW; ++nt)
                bfn[nt] = *(const short8*)(wpk +
                    ((size_t)((kt + 1) * NT + wave * NTW + nt) * 64 + lane) * 8);
        }
        short8 af[4];
#pragma unroll
        for (int mt = 0; mt < 4; ++mt)
            af[mt] = *(const short8*)(bufIn + (mt * 16 + lan) * HSTRIDE + kt * 32 + quad * 8);
#pragma unroll
        for (int nt = 0; nt < NTW; ++nt)
#pragma unroll
            for (int mt = 0; mt < 4; ++mt)
                acc[mt][nt] = __builtin_amdgcn_mfma_f32_16x16x32_bf16(af[mt], bfc[nt], acc[mt][nt], 0, 0, 0);
#pragma unroll
        for (int nt = 0; nt < NTW; ++nt) bfc[nt] = bfn[nt];
    }
    __builtin_amdgcn_s_setprio(0);

    // Prefetch next layer's kt=0 B-frags; epilogue below hides the latency.
#pragma unroll
    for (int nt = 0; nt < NNTW; ++nt)
        nbf0[nt] = *(const short8*)(nwpk + ((size_t)(wave * NNTW + nt) * 64 + lane) * 8);

    // No barrier needed here: bufOut is disjoint from bufIn.
#pragma unroll
    for (int np = 0; np < NTW / 2; ++np) {
        const int ntg   = wave * NTW + 2 * np;
        const float bA  = bias[ntg * 16 + lan];
        const float bB  = bias[ntg * 16 + 16 + lan];
        const int pcol  = (ntg >> 1) * 32 + 2 * lan;   // pair-interleaved physical col
#pragma unroll
        for (int mt = 0; mt < 4; ++mt)
#pragma unroll
            for (int r2 = 0; r2 < 4; ++r2) {
                float vA = acc[mt][2 * np][r2] + bA;
                vA = vA * __builtin_amdgcn_rcpf(1.f + __expf(-vA));
                float vB = acc[mt][2 * np + 1][r2] + bB;
                vB = vB * __builtin_amdgcn_rcpf(1.f + __expf(-vB));
                *(unsigned*)(bufOut + (mt * 16 + quad * 4 + r2) * HSTRIDE + pcol) = pk2(vA, vB);
            }
    }
    __syncthreads();   // publishes bufOut writes; retires bufIn reads
}

__device__ __forceinline__ float softplus_stable(float x) {
    return fmaxf(x, 0.f) + __logf(1.f + __expf(-fabsf(x)));
}

__global__ void __launch_bounds__(256, 2)
fused_ensemble(const float* __restrict__ state, const float* __restrict__ action,
               const float* __restrict__ b0, const float* __restrict__ b1,
               const float* __restrict__ b2, const float* __restrict__ b3,
               const float* __restrict__ bmu, const float* __restrict__ bsig,
               const float* __restrict__ maxls, const float* __restrict__ minls,
               const short* __restrict__ wpk,
               float* __restrict__ out_mu, float* __restrict__ out_sig) {
    __shared__ __align__(16) short hs[2][64 * HSTRIDE];   // ping-pong, 67.6KB
    short* hA = hs[0];
    short* hB = hs[1];
    const int tid  = threadIdx.x;
    const int wave = tid >> 6, lane = tid & 63;
    const int bid  = blockIdx.x;
    const int e    = bid >> 9;      // 512 row-blocks per ensemble
    const int r0   = (bid & 511) << 6;

    const short* wp = wpk + (size_t)e * PER_E;

    // Prefetch L0's kt=0 B-frags; input staging hides the latency.
    short8 fragA[4], fragB[4];
#pragma unroll
    for (int nt = 0; nt < 4; ++nt)
        fragA[nt] = *(const short8*)(wp + ((size_t)(wave * 4 + nt) * 64 + lane) * 8);

    // Stage input into hA: [state(32)|action(8)|zeros(24)] bf16; float2->bf16x2.
    for (int idx = tid; idx < 64 * 32; idx += 256) {   // 64 rows x 32 col-pairs
        int m = idx >> 5, cp = idx & 31;
        int row = r0 + m;
        float2 v;
        if (cp < 16)      v = ((const float2*)state)[row * 16 + cp];
        else if (cp < 20) v = ((const float2*)action)[row * 4 + (cp - 16)];
        else              v = make_float2(0.f, 0.f);
        *(unsigned*)(hA + m * HSTRIDE + 2 * cp) = pk2(v.x, v.y);
    }
    __syncthreads();

    // Ping-pong: A -> B -> A -> B -> A; head reads A.
    mlp_layer<2, 4, 16, 4>(wp,          b0 + e * 256, hA, hB, wave, lane, fragA, wp + 16384,  fragB);
    mlp_layer<8, 4, 16, 4>(wp + 16384,  b1 + e * 256, hB, hA, wave, lane, fragB, wp + 81920,  fragA);
    mlp_layer<8, 4, 16, 2>(wp + 81920,  b2 + e * 256, hA, hB, wave, lane, fragA, wp + 147456, fragB);
    mlp_layer<8, 2, 8, 1 >(wp + 147456, b3 + e * 128, hB, hA, wave, lane, fragB, wp + 180224, fragA);

    // Heads: K=128, combined N=64 (mu 0..31 | sig 32..63); wave w -> n-tile w.
    const int quad = lane >> 4, lan = lane & 15;
    floatx4 acc[4];
#pragma unroll
    for (int mt = 0; mt < 4; ++mt) acc[mt] = floatx4{0.f, 0.f, 0.f, 0.f};
    const short* wph = wp + 180224;
    short8 bhc = fragA[0], bhn;
#pragma unroll
    for (int kt = 0; kt < 4; ++kt) {
        if (kt < 3)
            bhn = *(const short8*)(wph + (((size_t)(kt + 1) * 4 + wave) * 64 + lane) * 8);
#pragma unroll
        for (int mt = 0; mt < 4; ++mt) {
            const short8 af = *(const short8*)(hA + (mt * 16 + lan) * HSTRIDE + kt * 32 + quad * 8);
            acc[mt] = __builtin_amdgcn_mfma_f32_16x16x32_bf16(af, bhc, acc[mt], 0, 0, 0);
        }
        bhc = bhn;
    }
    const int colw = wave * 16 + lan;   // 0..63 combined (logical)
    if (colw < 32) {                    // mu waves (0,1) — wave-uniform branch
        const int col = colw;
        const float bv = bmu[e * 32 + col];
#pragma unroll
        for (int mt = 0; mt < 4; ++mt)
#pragma unroll
            for (int r2 = 0; r2 < 4; ++r2) {
                int grow = r0 + mt * 16 + quad * 4 + r2;
                float v = acc[mt][r2] + bv + state[grow * 32 + col];   // residual
                out_mu[((size_t)e * NB + grow) * 32 + col] = v;
            }
    } else {                            // sigma waves (2,3)
        const int col = colw - 32;
        const float bv = bsig[e * 32 + col];
        const float mx = maxls[col], mn = minls[col];
#pragma unroll
        for (int mt = 0; mt < 4; ++mt)
#pragma unroll
            for (int r2 = 0; r2 < 4; ++r2) {
                int grow = r0 + mt * 16 + quad * 4 + r2;
                float ls = acc[mt][r2] + bv;
                ls = mx - softplus_stable(mx - ls);   // soft_clamp upper
                ls = mn + softplus_stable(ls - mn);   // soft_clamp lower
                out_sig[((size_t)e * NB + grow) * 32 + col] = __expf(ls);
            }
    }
}

extern "C" void kernel_launch(void* const* d_in, const int* in_sizes, int n_in,
                              void* d_out, int out_size, void* d_ws, size_t ws_size,
                              hipStream_t stream) {
    const float* state  = (const float*)d_in[0];
    const float* action = (const float*)d_in[1];
    const float* W0   = (const float*)d_in[2];
    const float* b0   = (const float*)d_in[3];
    const float* W1   = (const float*)d_in[4];
    const float* b1   = (const float*)d_in[5];
    const float* W2   = (const float*)d_in[6];
    const float* b2   = (const float*)d_in[7];
    const float* W3   = (const float*)d_in[8];
    const float* b3   = (const float*)d_in[9];
    const float* Wmu  = (const float*)d_in[10];
    const float* bmu  = (const float*)d_in[11];
    const float* Wsig = (const float*)d_in[12];
    const float* bsig = (const float*)d_in[13];
    const float* maxls = (const float*)d_in[14];
    const float* minls = (const float*)d_in[15];

    short* wpk = (short*)d_ws;                         // packed bf16 weights
    float* out_mu  = (float*)d_out;
    float* out_sig = out_mu + (size_t)NE * NB * 32;

    pack_w<<<NE * 92, 256, 0, stream>>>(W0, W1, W2, W3, Wmu, Wsig, wpk);
    fused_ensemble<<<NE * 512, 256, 0, stream>>>(state, action, b0, b1, b2, b3,
                                                 bmu, bsig, maxls, minls, wpk,
                                                 out_mu, out_sig);
}

// Round 4
// 227.077 us; speedup vs baseline: 1.1989x; 1.1989x over previous
//
#include <hip/hip_runtime.h>
#include <hip/hip_bf16.h>

// ---------------------------------------------------------------------------
// EnsembleDynamicModel: E=7 MLPs, B=32768, dims 40->256->256->256->128->(32|32)
// Fully fused bf16-MFMA kernel with register software-pipelining:
//   - B-fragments double-buffered one kt ahead (hides L2 latency in MFMA loop)
//   - next layer's kt=0 B-fragments prefetched BEFORE the swish epilogue
//     (the ~1000-cycle VALU epilogue hides the next layer's first load)
//
// Round 4: exact round-0 structure (144.6us baseline; rounds 1-3 structural
// variants all regressed: R1 spill, R2 LDS-traffic x2, R3 occupancy 12->8
// waves/CU). Additions only:
//   (a) s_setprio(1) around MFMA clusters (T5): 3 anti-phased blocks/CU give
//       wave role diversity {MFMA-phase vs epilogue-phase}; favor matrix pipe.
//   (b) epilogue bias values prefetched BEFORE the MFMA loop so their L2
//       latency never sits on the post-barrier epilogue critical path.
//
// Lessons encoded: occupancy (12 waves/CU) > barrier count; acc=64 AGPR is
// structural (4x4 tile needed for B-frag reuse + LDS A-read economy) ->
// 3 waves/EU is the register ceiling; do not trade residency for structure.
//
// Activation layout: pair-interleaved columns: n-tile ntg col c -> physical
// col 32*(ntg>>1) + 2c + (ntg&1); weight packer applies inverse permutation
// to k for layers reading hidden activations.
// ---------------------------------------------------------------------------

#define NE 7
#define NB 32768
#define PER_E 188416   // packed shorts per ensemble
#define HSTRIDE 264    // 256 + 8 pad (shorts)

typedef __attribute__((ext_vector_type(8))) short short8;   // 8 x bf16
typedef __attribute__((ext_vector_type(4))) float floatx4;  // MFMA C/D

__device__ __forceinline__ short f2b(float f) {
    union { float f; unsigned u; } c; c.f = f;
    return (short)((c.u + 0x7fffu + ((c.u >> 16) & 1u)) >> 16);
}
__device__ __forceinline__ unsigned pk2(float a, float b) {  // bf16x2 {lo=a,hi=b}
    union { __hip_bfloat162 h; unsigned u; } c;
    c.h = __float22bfloat162_rn(make_float2(a, b));
    return c.u;
}

// Packed-weight layout per ensemble (units: shorts):
//  L0 : off 0      KT=2 NT=16 Kact=40  N=256
//  L1 : off 16384  KT=8 NT=16 Kact=256 N=256
//  L2 : off 81920  KT=8 NT=16 Kact=256 N=256
//  L3 : off 147456 KT=8 NT=8  Kact=256 N=128
//  HD : off 180224 KT=4 NT=4  Kact=128 N=64   (mu cols 0..31 | sig 32..63)
__global__ void __launch_bounds__(256) pack_w(
    const float* __restrict__ W0, const float* __restrict__ W1,
    const float* __restrict__ W2, const float* __restrict__ W3,
    const float* __restrict__ Wmu, const float* __restrict__ Wsig,
    short* __restrict__ out)
{
    __shared__ float tile[32][65];
    const int t = threadIdx.x;
    int b = blockIdx.x;
    int e = b / 92;
    int r = b - e * 92;
    const float* src = W0;
    int off = 0, Kact = 40, N = 256, NT = 16, kt, ntb;
    bool inv = false, head = false;
    if (r < 8)       { kt = r >> 2; ntb = r & 3; }
    else if (r < 40) { r -= 8;  src = W1; off = 16384;  Kact = 256; kt = r >> 2; ntb = r & 3; inv = true; }
    else if (r < 72) { r -= 40; src = W2; off = 81920;  Kact = 256; kt = r >> 2; ntb = r & 3; inv = true; }
    else if (r < 88) { r -= 72; src = W3; off = 147456; Kact = 256; N = 128; NT = 8; kt = r >> 1; ntb = r & 1; inv = true; }
    else             { r -= 88; off = 180224; Kact = 128; N = 64; NT = 4; kt = r; ntb = 0; inv = true; head = true; }

#pragma unroll
    for (int i = 0; i < 8; ++i) {
        int elem  = t + i * 256;
        int row_l = elem >> 6, col_l = elem & 63;
        int gk = kt * 32 + row_l;
        int gn = ntb * 64 + col_l;
        float v = 0.f;
        if (gk < Kact) {
            if (head) v = (gn < 32) ? Wmu[((size_t)e * 128 + gk) * 32 + gn]
                                    : Wsig[((size_t)e * 128 + gk) * 32 + (gn - 32)];
            else      v = src[((size_t)e * Kact + gk) * N + gn];
        }
        tile[row_l][col_l] = v;
    }
    __syncthreads();

    const int f = t >> 6, lam = t & 63;
    const int lan = lam & 15, quad = lam >> 4;
    short8 o;
#pragma unroll
    for (int j = 0; j < 8; ++j) {
        int q  = quad * 8 + j;                              // physical k within 32-block
        int sr = inv ? (((q & 1) << 4) | (q >> 1)) : q;     // logical source row
        o[j] = f2b(tile[sr][f * 16 + lan]);
    }
    *(short8*)(out + (size_t)e * PER_E + off +
               ((size_t)(kt * NT + ntb * 4 + f) * 64 + lam) * 8) = o;
}

// One hidden layer. bf0[NTW]   : this layer's kt=0 B-fragments (prefetched).
//                  nbf0[NNTW]  : out — next layer's kt=0 B-frags, prefetched
//                                before the epilogue so swish hides L2 latency.
template<int KT, int NTW, int NT, int NNTW>
__device__ __forceinline__ void mlp_layer(const short* __restrict__ wpk,
                                          const float* __restrict__ bias,
                                          short* hs, const int wave, const int lane,
                                          const short8* bf0,
                                          const short* __restrict__ nwpk,
                                          short8* nbf0) {
    const int quad = lane >> 4;
    const int lan  = lane & 15;
    floatx4 acc[4][NTW];
#pragma unroll
    for (int mt = 0; mt < 4; ++mt)
#pragma unroll
        for (int nt = 0; nt < NTW; ++nt) acc[mt][nt] = floatx4{0.f, 0.f, 0.f, 0.f};

    // Prefetch epilogue bias early: L2 latency hides under the MFMA loop
    // instead of sitting on the post-barrier epilogue critical path.
    float bAv[NTW / 2], bBv[NTW / 2];
#pragma unroll
    for (int np = 0; np < NTW / 2; ++np) {
        const int ntg = wave * NTW + 2 * np;
        bAv[np] = bias[ntg * 16 + lan];
        bBv[np] = bias[ntg * 16 + 16 + lan];
    }

    short8 bfc[NTW], bfn[NTW];
#pragma unroll
    for (int nt = 0; nt < NTW; ++nt) bfc[nt] = bf0[nt];

    __builtin_amdgcn_s_setprio(1);   // T5: favor matrix pipe vs other blocks'
#pragma unroll                       // epilogue waves on the same SIMD
    for (int kt = 0; kt < KT; ++kt) {
        if (kt + 1 < KT) {   // prefetch next kt's B-frags before this kt's MFMAs
#pragma unroll
            for (int nt = 0; nt < NTW; ++nt)
                bfn[nt] = *(const short8*)(wpk +
                    ((size_t)((kt + 1) * NT + wave * NTW + nt) * 64 + lane) * 8);
        }
        short8 af[4];
#pragma unroll
        for (int mt = 0; mt < 4; ++mt)
            af[mt] = *(const short8*)(hs + (mt * 16 + lan) * HSTRIDE + kt * 32 + quad * 8);
#pragma unroll
        for (int nt = 0; nt < NTW; ++nt)
#pragma unroll
            for (int mt = 0; mt < 4; ++mt)
                acc[mt][nt] = __builtin_amdgcn_mfma_f32_16x16x32_bf16(af[mt], bfc[nt], acc[mt][nt], 0, 0, 0);
#pragma unroll
        for (int nt = 0; nt < NTW; ++nt) bfc[nt] = bfn[nt];
    }
    __builtin_amdgcn_s_setprio(0);

    // Prefetch next layer's kt=0 B-frags; epilogue below hides the latency.
#pragma unroll
    for (int nt = 0; nt < NNTW; ++nt)
        nbf0[nt] = *(const short8*)(nwpk + ((size_t)(wave * NNTW + nt) * 64 + lane) * 8);

    __syncthreads();   // all waves finished reading hs
#pragma unroll
    for (int np = 0; np < NTW / 2; ++np) {
        const int ntg   = wave * NTW + 2 * np;
        const float bA  = bAv[np];
        const float bB  = bBv[np];
        const int pcol  = (ntg >> 1) * 32 + 2 * lan;   // pair-interleaved physical col
#pragma unroll
        for (int mt = 0; mt < 4; ++mt)
#pragma unroll
            for (int r2 = 0; r2 < 4; ++r2) {
                float vA = acc[mt][2 * np][r2] + bA;
                vA = vA * __builtin_amdgcn_rcpf(1.f + __expf(-vA));
                float vB = acc[mt][2 * np + 1][r2] + bB;
                vB = vB * __builtin_amdgcn_rcpf(1.f + __expf(-vB));
                *(unsigned*)(hs + (mt * 16 + quad * 4 + r2) * HSTRIDE + pcol) = pk2(vA, vB);
            }
    }
    __syncthreads();   // writes visible before next layer reads
}

__device__ __forceinline__ float softplus_stable(float x) {
    return fmaxf(x, 0.f) + __logf(1.f + __expf(-fabsf(x)));
}

__global__ void __launch_bounds__(256, 3)
fused_ensemble(const float* __restrict__ state, const float* __restrict__ action,
               const float* __restrict__ b0, const float* __restrict__ b1,
               const float* __restrict__ b2, const float* __restrict__ b3,
               const float* __restrict__ bmu, const float* __restrict__ bsig,
               const float* __restrict__ maxls, const float* __restrict__ minls,
               const short* __restrict__ wpk,
               float* __restrict__ out_mu, float* __restrict__ out_sig) {
    __shared__ __align__(16) short hs[64 * HSTRIDE];
    const int tid  = threadIdx.x;
    const int wave = tid >> 6, lane = tid & 63;
    const int bid  = blockIdx.x;
    const int e    = bid >> 9;      // 512 row-blocks per ensemble
    const int r0   = (bid & 511) << 6;

    const short* wp = wpk + (size_t)e * PER_E;

    // Prefetch L0's kt=0 B-frags; input staging hides the latency.
    short8 fragA[4], fragB[4];
#pragma unroll
    for (int nt = 0; nt < 4; ++nt)
        fragA[nt] = *(const short8*)(wp + ((size_t)(wave * 4 + nt) * 64 + lane) * 8);

    // Stage input: [state(32) | action(8) | zeros(24)] bf16; float2 -> bf16x2.
    for (int idx = tid; idx < 64 * 32; idx += 256) {   // 64 rows x 32 col-pairs
        int m = idx >> 5, cp = idx & 31;
        int row = r0 + m;
        float2 v;
        if (cp < 16)      v = ((const float2*)state)[row * 16 + cp];
        else if (cp < 20) v = ((const float2*)action)[row * 4 + (cp - 16)];
        else              v = make_float2(0.f, 0.f);
        *(unsigned*)(hs + m * HSTRIDE + 2 * cp) = pk2(v.x, v.y);
    }
    __syncthreads();

    mlp_layer<2, 4, 16, 4>(wp,          b0 + e * 256, hs, wave, lane, fragA, wp + 16384,  fragB);
    mlp_layer<8, 4, 16, 4>(wp + 16384,  b1 + e * 256, hs, wave, lane, fragB, wp + 81920,  fragA);
    mlp_layer<8, 4, 16, 2>(wp + 81920,  b2 + e * 256, hs, wave, lane, fragA, wp + 147456, fragB);
    mlp_layer<8, 2, 8, 1 >(wp + 147456, b3 + e * 128, hs, wave, lane, fragB, wp + 180224, fragA);

    // Heads: K=128, combined N=64 (mu 0..31 | sig 32..63); wave w -> n-tile w.
    const int quad = lane >> 4, lan = lane & 15;
    floatx4 acc[4];
#pragma unroll
    for (int mt = 0; mt < 4; ++mt) acc[mt] = floatx4{0.f, 0.f, 0.f, 0.f};
    const short* wph = wp + 180224;
    short8 bhc = fragA[0], bhn;
    __builtin_amdgcn_s_setprio(1);
#pragma unroll
    for (int kt = 0; kt < 4; ++kt) {
        if (kt < 3)
            bhn = *(const short8*)(wph + (((size_t)(kt + 1) * 4 + wave) * 64 + lane) * 8);
#pragma unroll
        for (int mt = 0; mt < 4; ++mt) {
            const short8 af = *(const short8*)(hs + (mt * 16 + lan) * HSTRIDE + kt * 32 + quad * 8);
            acc[mt] = __builtin_amdgcn_mfma_f32_16x16x32_bf16(af, bhc, acc[mt], 0, 0, 0);
        }
        bhc = bhn;
    }
    __builtin_amdgcn_s_setprio(0);
    const int colw = wave * 16 + lan;   // 0..63 combined (logical)
    if (colw < 32) {                    // mu waves (0,1) — wave-uniform branch
        const int col = colw;
        const float bv = bmu[e * 32 + col];
#pragma unroll
        for (int mt = 0; mt < 4; ++mt)
#pragma unroll
            for (int r2 = 0; r2 < 4; ++r2) {
                int grow = r0 + mt * 16 + quad * 4 + r2;
                float v = acc[mt][r2] + bv + state[grow * 32 + col];   // residual
                out_mu[((size_t)e * NB + grow) * 32 + col] = v;
            }
    } else {                            // sigma waves (2,3)
        const int col = colw - 32;
        const float bv = bsig[e * 32 + col];
        const float mx = maxls[col], mn = minls[col];
#pragma unroll
        for (int mt = 0; mt < 4; ++mt)
#pragma unroll
            for (int r2 = 0; r2 < 4; ++r2) {
                int grow = r0 + mt * 16 + quad * 4 + r2;
                float ls = acc[mt][r2] + bv;
                ls = mx - softplus_stable(mx - ls);   // soft_clamp upper
                ls = mn + softplus_stable(ls - mn);   // soft_clamp lower
                out_sig[((size_t)e * NB + grow) * 32 + col] = __expf(ls);
            }
    }
}

extern "C" void kernel_launch(void* const* d_in, const int* in_sizes, int n_in,
                              void* d_out, int out_size, void* d_ws, size_t ws_size,
                              hipStream_t stream) {
    const float* state  = (const float*)d_in[0];
    const float* action = (const float*)d_in[1];
    const float* W0   = (const float*)d_in[2];
    const float* b0   = (const float*)d_in[3];
    const float* W1   = (const float*)d_in[4];
    const float* b1   = (const float*)d_in[5];
    const float* W2   = (const float*)d_in[6];
    const float* b2   = (const float*)d_in[7];
    const float* W3   = (const float*)d_in[8];
    const float* b3   = (const float*)d_in[9];
    const float* Wmu  = (const float*)d_in[10];
    const float* bmu  = (const float*)d_in[11];
    const float* Wsig = (const float*)d_in[12];
    const float* bsig = (const float*)d_in[13];
    const float* maxls = (const float*)d_in[14];
    const float* minls = (const float*)d_in[15];

    short* wpk = (short*)d_ws;                         // packed bf16 weights
    float* out_mu  = (float*)d_out;
    float* out_sig = out_mu + (size_t)NE * NB * 32;

    pack_w<<<NE * 92, 256, 0, stream>>>(W0, W1, W2, W3, Wmu, Wsig, wpk);
    fused_ensemble<<<NE * 512, 256, 0, stream>>>(state, action, b0, b1, b2, b3,
                                                 bmu, bsig, maxls, minls, wpk,
                                                 out_mu, out_sig);
}